// Round 1
// baseline (163.133 us; speedup 1.0000x reference)
//
#include <hip/hip_runtime.h>

#define NROWS 384
#define DDIM  768
#define TILE  32
#define LDP   36   // padded LDS row (floats), 16B-aligned, breaks pow2 banking

// ---------------------------------------------------------------------------
// K1: A'[i][od] = sum_k p[i][k] * W1[od][k]        + b1[od]   (g==0)
//     B [i][od] = sum_k p[i][k] * W1[od][768 + k]             (g==1)
// outAB layout: A' at [0, 384*768), B at [384*768, 2*384*768)
// 32x32 output tile per 64-thread block; 4x4 register tile per thread.
// ---------------------------------------------------------------------------
__global__ __launch_bounds__(64) void k1_gemm(
    const float* __restrict__ p, const float* __restrict__ W1,
    const float* __restrict__ b1, float* __restrict__ outAB) {
  const int ib = blockIdx.x;   // i-tile  (0..11)
  const int ob = blockIdx.y;   // od-tile (0..23)
  const int g  = blockIdx.z;   // 0 = A half, 1 = B half

  __shared__ float pT[TILE][LDP];  // pT[k][i]
  __shared__ float wT[TILE][LDP];  // wT[k][od]

  const int t  = threadIdx.x;
  const int i0 = (t & 7) * 4;   // thread tile offsets inside 32x32
  const int o0 = (t >> 3) * 4;
  const int iBase = ib * TILE;
  const int oBase = ob * TILE;

  float acc[4][4] = {};

  const int kk = (t & 7) * 4;   // staging: col group
  const int rr = t >> 3;        // staging: row within pass

  for (int k0 = 0; k0 < DDIM; k0 += TILE) {
    // stage 32x32 of p and W1 (transposed in k) into LDS
    #pragma unroll
    for (int rp = 0; rp < TILE; rp += 8) {
      const int row = rr + rp;
      const float4 v = *(const float4*)&p[(size_t)(iBase + row) * DDIM + k0 + kk];
      pT[kk + 0][row] = v.x; pT[kk + 1][row] = v.y;
      pT[kk + 2][row] = v.z; pT[kk + 3][row] = v.w;
      const float4 w = *(const float4*)&W1[(size_t)(oBase + row) * (2 * DDIM) + g * DDIM + k0 + kk];
      wT[kk + 0][row] = w.x; wT[kk + 1][row] = w.y;
      wT[kk + 2][row] = w.z; wT[kk + 3][row] = w.w;
    }
    __syncthreads();

    #pragma unroll 8
    for (int k = 0; k < TILE; ++k) {
      float a[4], b[4];
      *(float4*)a = *(const float4*)&pT[k][i0];
      *(float4*)b = *(const float4*)&wT[k][o0];
      #pragma unroll
      for (int ii = 0; ii < 4; ++ii)
        #pragma unroll
        for (int oo = 0; oo < 4; ++oo)
          acc[ii][oo] = fmaf(a[ii], b[oo], acc[ii][oo]);
    }
    __syncthreads();
  }

  float* dst = outAB + (size_t)g * (NROWS * DDIM);
  const int col = oBase + o0;
  #pragma unroll
  for (int ii = 0; ii < 4; ++ii) {
    const int row = iBase + i0 + ii;
    float4 r;
    r.x = acc[ii][0]; r.y = acc[ii][1]; r.z = acc[ii][2]; r.w = acc[ii][3];
    if (g == 0) {  // fold b1 into A'
      r.x += b1[col + 0]; r.y += b1[col + 1];
      r.z += b1[col + 2]; r.w += b1[col + 3];
    }
    *(float4*)&dst[(size_t)row * DDIM + col] = r;
  }
}

// ---------------------------------------------------------------------------
// K2: logits[i][j][c] = sum_d tanh(A'[i][d] + B[j][d]) * W2[c][d] + b2[c]
// wave -> i (uniform), lane -> j. A'/W2 rows wave-uniform (scalar loads);
// B rows per-lane, L1-resident. No cross-lane reduction needed.
// ---------------------------------------------------------------------------
__device__ __forceinline__ float fast_tanh(float s) {
  // tanh(s) = 1 - 2/(exp(2s)+1); v_exp_f32 computes 2^x
  const float e = __builtin_amdgcn_exp2f(s * 2.88539008177793f);  // 2*log2(e)
  return 1.0f - 2.0f * __builtin_amdgcn_rcpf(e + 1.0f);
}

__global__ __launch_bounds__(256) void k2_fused(
    const float* __restrict__ AB, const float* __restrict__ W2,
    const float* __restrict__ b2, float* __restrict__ out) {
  const int lane = threadIdx.x & 63;
  const int wave = threadIdx.x >> 6;
  const int i = __builtin_amdgcn_readfirstlane(blockIdx.x * 4 + wave);
  const int j = blockIdx.y * 64 + lane;

  const float* __restrict__ Ap  = AB + (size_t)i * DDIM;                 // uniform
  const float* __restrict__ Bp  = AB + (size_t)(NROWS * DDIM) + (size_t)j * DDIM;
  const float* __restrict__ w0p = W2;                                     // uniform
  const float* __restrict__ w1p = W2 + DDIM;                              // uniform

  float acc0[4] = {}, acc1[4] = {};

  for (int d = 0; d < DDIM; d += 4) {
    const float4 b4  = *(const float4*)&Bp[d];
    const float4 a4  = *(const float4*)&Ap[d];
    const float4 w04 = *(const float4*)&w0p[d];
    const float4 w14 = *(const float4*)&w1p[d];

    float t;
    t = fast_tanh(a4.x + b4.x); acc0[0] = fmaf(t, w04.x, acc0[0]); acc1[0] = fmaf(t, w14.x, acc1[0]);
    t = fast_tanh(a4.y + b4.y); acc0[1] = fmaf(t, w04.y, acc0[1]); acc1[1] = fmaf(t, w14.y, acc1[1]);
    t = fast_tanh(a4.z + b4.z); acc0[2] = fmaf(t, w04.z, acc0[2]); acc1[2] = fmaf(t, w14.z, acc1[2]);
    t = fast_tanh(a4.w + b4.w); acc0[3] = fmaf(t, w04.w, acc0[3]); acc1[3] = fmaf(t, w14.w, acc1[3]);
  }

  float2 r;
  r.x = (acc0[0] + acc0[1]) + (acc0[2] + acc0[3]) + b2[0];
  r.y = (acc1[0] + acc1[1]) + (acc1[2] + acc1[3]) + b2[1];
  *(float2*)&out[((size_t)i * NROWS + j) * 2] = r;
}

// ---------------------------------------------------------------------------
extern "C" void kernel_launch(void* const* d_in, const int* in_sizes, int n_in,
                              void* d_out, int out_size, void* d_ws, size_t ws_size,
                              hipStream_t stream) {
  const float* p  = (const float*)d_in[0];   // [384, 768]
  const float* W1 = (const float*)d_in[1];   // [768, 1536]
  const float* b1 = (const float*)d_in[2];   // [768]
  const float* W2 = (const float*)d_in[3];   // [2, 768]
  const float* b2 = (const float*)d_in[4];   // [2]
  float* out = (float*)d_out;                // [384, 384, 2]
  float* ws  = (float*)d_ws;                 // A' (384*768) then B (384*768)

  dim3 g1(NROWS / TILE, DDIM / TILE, 2);     // 12 x 24 x 2
  k1_gemm<<<g1, 64, 0, stream>>>(p, W1, b1, ws);

  dim3 g2(NROWS / 4, NROWS / 64);            // 96 x 6
  k2_fused<<<g2, 256, 0, stream>>>(ws, W2, b2, out);
}